// Round 1
// baseline (1665.383 us; speedup 1.0000x reference)
//
#include <hip/hip_runtime.h>

#define HIDDEN 64
#define IN_DIM 512

// ---------------- init: deg=1 (self loop), zero pool accumulators ----------
__global__ void k_init(int* deg, float* gsum, int* gcnt, int n_nodes) {
    int i = blockIdx.x * blockDim.x + threadIdx.x;
    if (i < n_nodes) deg[i] = 1;
    if (i < 256) { gsum[i] = 0.f; gcnt[i] = 0; }
}

// ---------------- in-degree histogram over dst --------------------------
__global__ void k_deg(const int* __restrict__ dst, int* deg, int n_edges) {
    int e = blockIdx.x * blockDim.x + threadIdx.x;
    if (e < n_edges) atomicAdd(&deg[dst[e]], 1);
}

__global__ void k_dinv(const int* __restrict__ deg, float* dinv, int n_nodes) {
    int i = blockIdx.x * blockDim.x + threadIdx.x;
    if (i < n_nodes) dinv[i] = rsqrtf((float)deg[i]);
}

// ---------------- GEMM1: s1 = dinv .* (x @ W1); acc init = s1 -------------
// block = 256 threads, 32 rows/block, K staged in chunks of 128.
#define G1_ROWS 32
#define G1_KC   128

__launch_bounds__(256)
__global__ void k_gemm1(const float* __restrict__ x, const float* __restrict__ W1,
                        const float* __restrict__ dinv,
                        float* __restrict__ s1, float* __restrict__ acc,
                        int n_nodes) {
    __shared__ float ldsW[G1_KC * HIDDEN];          // [k][f]  32 KB
    __shared__ float ldsX[G1_KC * (G1_ROWS + 1)];   // [k][r] pitch 33, ~16.5 KB
    const int tid  = threadIdx.x;
    const int row0 = blockIdx.x * G1_ROWS;
    const int r    = tid & 31;          // row within tile
    const int f0   = (tid >> 5) * 8;    // 8 output features per thread

    float acc8[8];
#pragma unroll
    for (int j = 0; j < 8; ++j) acc8[j] = 0.f;

    for (int kc = 0; kc < IN_DIM; kc += G1_KC) {
        __syncthreads();
        // stage W1 chunk [128][64] : 2048 float4, 8 per thread (coalesced)
        {
            const float4* Wg = (const float4*)(W1 + (size_t)kc * HIDDEN);
            float4* Wl = (float4*)ldsW;
#pragma unroll
            for (int i = 0; i < 8; ++i) Wl[tid + i * 256] = Wg[tid + i * 256];
        }
        // stage x chunk transposed into [k][r] (pitch 33: bank-conflict-free reads)
        {
            int f4 = tid & 31;   // float4 index along k (0..31)
            int rr = tid >> 5;   // 0..7
#pragma unroll
            for (int i = 0; i < 4; ++i) {
                int rowi = rr + i * 8;
                int grow = row0 + rowi;
                float4 v = make_float4(0.f, 0.f, 0.f, 0.f);
                if (grow < n_nodes)
                    v = ((const float4*)(x + (size_t)grow * IN_DIM + kc))[f4];
                int kk = f4 * 4;
                ldsX[(kk + 0) * (G1_ROWS + 1) + rowi] = v.x;
                ldsX[(kk + 1) * (G1_ROWS + 1) + rowi] = v.y;
                ldsX[(kk + 2) * (G1_ROWS + 1) + rowi] = v.z;
                ldsX[(kk + 3) * (G1_ROWS + 1) + rowi] = v.w;
            }
        }
        __syncthreads();
#pragma unroll 4
        for (int k = 0; k < G1_KC; ++k) {
            float xv = ldsX[k * (G1_ROWS + 1) + r];
            const float4* w4 = (const float4*)(ldsW + k * HIDDEN + f0);
            float4 wa = w4[0], wb = w4[1];
            acc8[0] += xv * wa.x; acc8[1] += xv * wa.y;
            acc8[2] += xv * wa.z; acc8[3] += xv * wa.w;
            acc8[4] += xv * wb.x; acc8[5] += xv * wb.y;
            acc8[6] += xv * wb.z; acc8[7] += xv * wb.w;
        }
    }

    int row = row0 + r;
    if (row < n_nodes) {
        float d = dinv[row];
        float4 o0 = make_float4(acc8[0] * d, acc8[1] * d, acc8[2] * d, acc8[3] * d);
        float4 o1 = make_float4(acc8[4] * d, acc8[5] * d, acc8[6] * d, acc8[7] * d);
        float4* sp = (float4*)(s1  + (size_t)row * HIDDEN + f0);
        float4* ap = (float4*)(acc + (size_t)row * HIDDEN + f0);
        sp[0] = o0; sp[1] = o1;
        ap[0] = o0; ap[1] = o1;
    }
}

// ---------------- edge scatter: acc[dst] += s[src] (per-feature atomics) ---
// one wave = one edge (64 features). gather + RMW both 256B coalesced.
__global__ void k_scatter(const int* __restrict__ src, const int* __restrict__ dst,
                          const float* __restrict__ s, float* acc,
                          int n_edges) {
    long long idx = (long long)blockIdx.x * blockDim.x + threadIdx.x;
    int e = (int)(idx >> 6);
    int f = (int)(idx & 63);
    if (e < n_edges) {
        int sv = src[e], dv = dst[e];
        atomicAdd(&acc[(size_t)dv * HIDDEN + f], s[(size_t)sv * HIDDEN + f]);
    }
}

// ---------------- layer-1 finalize fused with GEMM2 ----------------------
// h1 = relu(dinv*accIn + b1);  s2 = dinv .* (h1 @ W2); accOut(row)=s2(row).
// accIn/accOut may alias (in-place per-row, each row touched by one thread).
#define G2_ROWS 16

__launch_bounds__(256)
__global__ void k_gemm2(const float* accIn, const float* __restrict__ W2,
                        const float* __restrict__ b1, const float* __restrict__ dinv,
                        float* __restrict__ s2, float* accOut,
                        int n_nodes) {
    __shared__ float ldsW[HIDDEN * HIDDEN];   // 16 KB [k][f]
    const int tid = threadIdx.x;
    {
        const float4* Wg = (const float4*)W2;
        float4* Wl = (float4*)ldsW;
#pragma unroll
        for (int i = 0; i < 4; ++i) Wl[tid + i * 256] = Wg[tid + i * 256];
    }
    __syncthreads();
    const int lane = tid & 63;
    const int wave = tid >> 6;
    const float bias = b1[lane];
    for (int i = 0; i < 4; ++i) {
        int row = blockIdx.x * G2_ROWS + wave * 4 + i;
        if (row >= n_nodes) return;
        float d = dinv[row];
        float v = accIn[(size_t)row * HIDDEN + lane];
        float h = fmaxf(d * v + bias, 0.f);
        float a = 0.f;
#pragma unroll
        for (int k = 0; k < HIDDEN; ++k) {
            float hk = __shfl(h, k, 64);
            a += hk * ldsW[k * HIDDEN + lane];
        }
        float o = a * d;
        s2[(size_t)row * HIDDEN + lane]    = o;
        accOut[(size_t)row * HIDDEN + lane] = o;
    }
}

// ---------------- layer-2 finalize + mean-pool + FC ----------------------
// per node: t = sum_f relu(dinv*acc+b2)[f] * Wfc[f]; atomic into graph bins.
__global__ void k_pool(const float* __restrict__ acc, const float* __restrict__ b2,
                       const float* __restrict__ dinv, const float* __restrict__ Wfc,
                       const int* __restrict__ batch,
                       float* gsum, int* gcnt, int n_nodes) {
    int node = blockIdx.x * 4 + (threadIdx.x >> 6);
    int lane = threadIdx.x & 63;
    if (node >= n_nodes) return;
    float d = dinv[node];
    float v = acc[(size_t)node * HIDDEN + lane];
    float h = fmaxf(d * v + b2[lane], 0.f);
    float t = h * Wfc[lane];
#pragma unroll
    for (int off = 32; off > 0; off >>= 1) t += __shfl_down(t, off, 64);
    if (lane == 0) {
        int g = batch[node];
        atomicAdd(&gsum[g], t);
        atomicAdd(&gcnt[g], 1);
    }
}

__global__ void k_out(const float* __restrict__ gsum, const int* __restrict__ gcnt,
                      const float* __restrict__ bfc, float* out) {
    int g = threadIdx.x;
    if (g < 256) {
        float c = (float)(gcnt[g] > 1 ? gcnt[g] : 1);
        out[g] = gsum[g] / c + bfc[0];
    }
}

// ---------------------------------------------------------------------------
extern "C" void kernel_launch(void* const* d_in, const int* in_sizes, int n_in,
                              void* d_out, int out_size, void* d_ws, size_t ws_size,
                              hipStream_t stream) {
    const float* x   = (const float*)d_in[0];
    const int*   ei  = (const int*)d_in[1];
    const int*   bat = (const int*)d_in[2];
    const float* W1  = (const float*)d_in[3];
    const float* b1  = (const float*)d_in[4];
    const float* W2  = (const float*)d_in[5];
    const float* b2  = (const float*)d_in[6];
    const float* Wfc = (const float*)d_in[7];
    const float* bfc = (const float*)d_in[8];
    float* out = (float*)d_out;

    const int n_nodes = in_sizes[2];
    const int n_edges = in_sizes[1] / 2;
    const int* src = ei;
    const int* dst = ei + n_edges;

    // workspace layout (all 256B aligned)
    char* w = (char*)d_ws;
    size_t off = 0;
    auto alloc = [&](size_t bytes) -> void* {
        void* p = w + off;
        off += (bytes + 255) & ~(size_t)255;
        return p;
    };
    int*   deg  = (int*)  alloc((size_t)n_nodes * sizeof(int));
    float* dinv = (float*)alloc((size_t)n_nodes * sizeof(float));
    float* bufA = (float*)alloc((size_t)n_nodes * HIDDEN * sizeof(float)); // s1 then s2
    float* bufB = (float*)alloc((size_t)n_nodes * HIDDEN * sizeof(float)); // acc1 then acc2
    float* gsum = (float*)alloc(256 * sizeof(float));
    int*   gcnt = (int*)  alloc(256 * sizeof(int));
    (void)ws_size; (void)n_in; (void)out_size;

    const int nb = (n_nodes + 255) / 256;
    hipLaunchKernelGGL(k_init, dim3(nb), dim3(256), 0, stream, deg, gsum, gcnt, n_nodes);
    hipLaunchKernelGGL(k_deg, dim3((n_edges + 255) / 256), dim3(256), 0, stream,
                       dst, deg, n_edges);
    hipLaunchKernelGGL(k_dinv, dim3(nb), dim3(256), 0, stream, deg, dinv, n_nodes);

    hipLaunchKernelGGL(k_gemm1, dim3((n_nodes + G1_ROWS - 1) / G1_ROWS), dim3(256), 0, stream,
                       x, W1, dinv, bufA, bufB, n_nodes);

    long long items = (long long)n_edges * 64;
    int sb = (int)((items + 255) / 256);
    hipLaunchKernelGGL(k_scatter, dim3(sb), dim3(256), 0, stream,
                       src, dst, bufA, bufB, n_edges);

    hipLaunchKernelGGL(k_gemm2, dim3((n_nodes + G2_ROWS - 1) / G2_ROWS), dim3(256), 0, stream,
                       bufB, W2, b1, dinv, bufA, bufB, n_nodes);

    hipLaunchKernelGGL(k_scatter, dim3(sb), dim3(256), 0, stream,
                       src, dst, bufA, bufB, n_edges);

    hipLaunchKernelGGL(k_pool, dim3((n_nodes + 3) / 4), dim3(256), 0, stream,
                       bufB, b2, dinv, Wfc, bat, gsum, gcnt, n_nodes);
    hipLaunchKernelGGL(k_out, dim3(1), dim3(256), 0, stream, gsum, gcnt, bfc, out);
}

// Round 2
// 794.923 us; speedup vs baseline: 2.0950x; 2.0950x over previous
//
#include <hip/hip_runtime.h>

#define HIDDEN 64
#define IN_DIM 512
#define SCAN_ITEMS 1024

// ---------------- init: deg=1 (self loop), zero pool accumulators ----------
__global__ void k_init(int* deg, float* gsum, int* gcnt, int n_nodes) {
    int i = blockIdx.x * blockDim.x + threadIdx.x;
    if (i < n_nodes) deg[i] = 1;
    if (i < 256) { gsum[i] = 0.f; gcnt[i] = 0; }
}

// ---------------- in-degree histogram over dst --------------------------
__global__ void k_deg(const int* __restrict__ dst, int* deg, int n_edges) {
    int e = blockIdx.x * blockDim.x + threadIdx.x;
    if (e < n_edges) atomicAdd(&deg[dst[e]], 1);
}

__global__ void k_dinv(const int* __restrict__ deg, float* dinv, int n_nodes) {
    int i = blockIdx.x * blockDim.x + threadIdx.x;
    if (i < n_nodes) dinv[i] = rsqrtf((float)deg[i]);
}

// ---------------- CSR build: 3-kernel exclusive scan of (deg-1) -----------
__global__ void k_scan1(const int* __restrict__ deg, int* bsum, int n) {
    int b = blockIdx.x, t = threadIdx.x;
    int base = b * SCAN_ITEMS;
    int s = 0;
    for (int i = t; i < SCAN_ITEMS; i += 256) {
        int g = base + i;
        if (g < n) s += deg[g] - 1;
    }
#pragma unroll
    for (int off = 32; off; off >>= 1) s += __shfl_down(s, off, 64);
    __shared__ int ws[4];
    if ((t & 63) == 0) ws[t >> 6] = s;
    __syncthreads();
    if (t == 0) bsum[b] = ws[0] + ws[1] + ws[2] + ws[3];
}

__global__ void k_scan2(int* bsum, int nb, int* row_start, int n_nodes, int n_edges) {
    if (threadIdx.x == 0) {
        int run = 0;
        for (int i = 0; i < nb; ++i) { int v = bsum[i]; bsum[i] = run; run += v; }
        row_start[n_nodes] = n_edges;
    }
}

__launch_bounds__(256)
__global__ void k_scan3(const int* __restrict__ deg, const int* __restrict__ bsum_ex,
                        int* row_start, int* cursor, float* dinv, int n) {
    int b = blockIdx.x, t = threadIdx.x;
    int i0 = b * SCAN_ITEMS + t * 4;
    int c[4], sinc[4];
#pragma unroll
    for (int k = 0; k < 4; ++k) { int g = i0 + k; c[k] = (g < n) ? deg[g] - 1 : 0; }
    sinc[0] = c[0];
    sinc[1] = sinc[0] + c[1];
    sinc[2] = sinc[1] + c[2];
    sinc[3] = sinc[2] + c[3];
    int S = sinc[3];
    int v = S, lane = t & 63;
#pragma unroll
    for (int off = 1; off < 64; off <<= 1) {
        int u = __shfl_up(v, off, 64);
        if (lane >= off) v += u;
    }
    int wave_excl = v - S;
    __shared__ int wtot[4];
    if (lane == 63) wtot[t >> 6] = v;
    __syncthreads();
    int cross = 0;
    for (int w = 0; w < (t >> 6); ++w) cross += wtot[w];
    int base = bsum_ex[b] + cross + wave_excl;
#pragma unroll
    for (int k = 0; k < 4; ++k) {
        int g = i0 + k;
        if (g < n) {
            int rsv = base + sinc[k] - c[k];
            row_start[g] = rsv;
            cursor[g] = rsv;
            dinv[g] = rsqrtf((float)deg[g]);
        }
    }
}

__global__ void k_fill(const int* __restrict__ src, const int* __restrict__ dst,
                       int* cursor, int* csr, int n_edges) {
    int e = blockIdx.x * blockDim.x + threadIdx.x;
    if (e < n_edges) {
        int d = dst[e];
        int pos = atomicAdd(&cursor[d], 1);
        csr[pos] = src[e];
    }
}

// ---------------- GEMM1: s1 = dinv .* (x @ W1); optional acc init ---------
#define G1_ROWS 32
#define G1_KC   128

__launch_bounds__(256)
__global__ void k_gemm1(const float* __restrict__ x, const float* __restrict__ W1,
                        const float* __restrict__ dinv,
                        float* __restrict__ s1, float* acc,
                        int n_nodes) {
    __shared__ float ldsW[G1_KC * HIDDEN];
    __shared__ float ldsX[G1_KC * (G1_ROWS + 1)];
    const int tid  = threadIdx.x;
    const int row0 = blockIdx.x * G1_ROWS;
    const int r    = tid & 31;
    const int f0   = (tid >> 5) * 8;

    float acc8[8];
#pragma unroll
    for (int j = 0; j < 8; ++j) acc8[j] = 0.f;

    for (int kc = 0; kc < IN_DIM; kc += G1_KC) {
        __syncthreads();
        {
            const float4* Wg = (const float4*)(W1 + (size_t)kc * HIDDEN);
            float4* Wl = (float4*)ldsW;
#pragma unroll
            for (int i = 0; i < 8; ++i) Wl[tid + i * 256] = Wg[tid + i * 256];
        }
        {
            int f4 = tid & 31;
            int rr = tid >> 5;
#pragma unroll
            for (int i = 0; i < 4; ++i) {
                int rowi = rr + i * 8;
                int grow = row0 + rowi;
                float4 v = make_float4(0.f, 0.f, 0.f, 0.f);
                if (grow < n_nodes)
                    v = ((const float4*)(x + (size_t)grow * IN_DIM + kc))[f4];
                int kk = f4 * 4;
                ldsX[(kk + 0) * (G1_ROWS + 1) + rowi] = v.x;
                ldsX[(kk + 1) * (G1_ROWS + 1) + rowi] = v.y;
                ldsX[(kk + 2) * (G1_ROWS + 1) + rowi] = v.z;
                ldsX[(kk + 3) * (G1_ROWS + 1) + rowi] = v.w;
            }
        }
        __syncthreads();
#pragma unroll 4
        for (int k = 0; k < G1_KC; ++k) {
            float xv = ldsX[k * (G1_ROWS + 1) + r];
            const float4* w4 = (const float4*)(ldsW + k * HIDDEN + f0);
            float4 wa = w4[0], wb = w4[1];
            acc8[0] += xv * wa.x; acc8[1] += xv * wa.y;
            acc8[2] += xv * wa.z; acc8[3] += xv * wa.w;
            acc8[4] += xv * wb.x; acc8[5] += xv * wb.y;
            acc8[6] += xv * wb.z; acc8[7] += xv * wb.w;
        }
    }

    int row = row0 + r;
    if (row < n_nodes) {
        float d = dinv[row];
        float4 o0 = make_float4(acc8[0] * d, acc8[1] * d, acc8[2] * d, acc8[3] * d);
        float4 o1 = make_float4(acc8[4] * d, acc8[5] * d, acc8[6] * d, acc8[7] * d);
        float4* sp = (float4*)(s1 + (size_t)row * HIDDEN + f0);
        sp[0] = o0; sp[1] = o1;
        if (acc) {
            float4* ap = (float4*)(acc + (size_t)row * HIDDEN + f0);
            ap[0] = o0; ap[1] = o1;
        }
    }
}

// ---------------- CSR path: layer1 gather + finalize + GEMM2 --------------
#define NPW 8   // nodes per wave

__launch_bounds__(256)
__global__ void k_layer1(const float* __restrict__ sin, const int* __restrict__ row_start,
                         const int* __restrict__ csr, const float* __restrict__ W2,
                         const float* __restrict__ b1, const float* __restrict__ dinv,
                         float* __restrict__ sout, int n_nodes) {
    __shared__ float ldsW[HIDDEN * HIDDEN];
    const int tid = threadIdx.x;
    {
        const float4* Wg = (const float4*)W2;
        float4* Wl = (float4*)ldsW;
#pragma unroll
        for (int i = 0; i < 4; ++i) Wl[tid + i * 256] = Wg[tid + i * 256];
    }
    __syncthreads();
    const int lane = tid & 63;
    const int wave = tid >> 6;
    const float bias = b1[lane];
    const int n0 = (blockIdx.x * 4 + wave) * NPW;
    for (int i = 0; i < NPW; ++i) {
        int n = n0 + i;
        if (n >= n_nodes) break;
        int rs = row_start[n], re = row_start[n + 1];
        float acc = sin[(size_t)n * HIDDEN + lane];   // self loop
        for (int base = rs; base < re; base += 64) {
            int idx = csr[base + lane];               // padded allocation
            int m = re - base; if (m > 64) m = 64;
            int j = 0;
            for (; j + 4 <= m; j += 4) {
                int a0 = __shfl(idx, j, 64),     a1 = __shfl(idx, j + 1, 64);
                int a2 = __shfl(idx, j + 2, 64), a3 = __shfl(idx, j + 3, 64);
                float v0 = sin[(size_t)a0 * HIDDEN + lane];
                float v1 = sin[(size_t)a1 * HIDDEN + lane];
                float v2 = sin[(size_t)a2 * HIDDEN + lane];
                float v3 = sin[(size_t)a3 * HIDDEN + lane];
                acc += (v0 + v1) + (v2 + v3);
            }
            for (; j < m; ++j) {
                int a0 = __shfl(idx, j, 64);
                acc += sin[(size_t)a0 * HIDDEN + lane];
            }
        }
        float d = dinv[n];
        float h = fmaxf(fmaf(d, acc, bias), 0.f);
        float a = 0.f;
#pragma unroll
        for (int k = 0; k < HIDDEN; ++k)
            a = fmaf(__shfl(h, k, 64), ldsW[k * HIDDEN + lane], a);
        sout[(size_t)n * HIDDEN + lane] = a * d;
    }
}

// ---------------- CSR path: layer2 gather + finalize + Wfc dot + pool -----
__launch_bounds__(256)
__global__ void k_layer2pool(const float* __restrict__ sin, const int* __restrict__ row_start,
                             const int* __restrict__ csr, const float* __restrict__ b2,
                             const float* __restrict__ dinv, const float* __restrict__ Wfc,
                             const int* __restrict__ batch,
                             float* gsum, int* gcnt, int n_nodes) {
    __shared__ float lsum[256];
    __shared__ int   lcnt[256];
    const int tid = threadIdx.x;
    if (tid < 256) { lsum[tid] = 0.f; lcnt[tid] = 0; }
    __syncthreads();
    const int lane = tid & 63;
    const int wave = tid >> 6;
    const float bias = b2[lane];
    const float wf = Wfc[lane];
    const int n0 = (blockIdx.x * 4 + wave) * NPW;
    for (int i = 0; i < NPW; ++i) {
        int n = n0 + i;
        if (n >= n_nodes) break;
        int rs = row_start[n], re = row_start[n + 1];
        float acc = sin[(size_t)n * HIDDEN + lane];
        for (int base = rs; base < re; base += 64) {
            int idx = csr[base + lane];
            int m = re - base; if (m > 64) m = 64;
            int j = 0;
            for (; j + 4 <= m; j += 4) {
                int a0 = __shfl(idx, j, 64),     a1 = __shfl(idx, j + 1, 64);
                int a2 = __shfl(idx, j + 2, 64), a3 = __shfl(idx, j + 3, 64);
                float v0 = sin[(size_t)a0 * HIDDEN + lane];
                float v1 = sin[(size_t)a1 * HIDDEN + lane];
                float v2 = sin[(size_t)a2 * HIDDEN + lane];
                float v3 = sin[(size_t)a3 * HIDDEN + lane];
                acc += (v0 + v1) + (v2 + v3);
            }
            for (; j < m; ++j) {
                int a0 = __shfl(idx, j, 64);
                acc += sin[(size_t)a0 * HIDDEN + lane];
            }
        }
        float d = dinv[n];
        float h = fmaxf(fmaf(d, acc, bias), 0.f);
        float t = h * wf;
#pragma unroll
        for (int off = 32; off; off >>= 1) t += __shfl_down(t, off, 64);
        if (lane == 0) {
            int g = batch[n];
            atomicAdd(&lsum[g], t);
            atomicAdd(&lcnt[g], 1);
        }
    }
    __syncthreads();
    if (tid < 256 && lcnt[tid]) {
        atomicAdd(&gsum[tid], lsum[tid]);
        atomicAdd(&gcnt[tid], lcnt[tid]);
    }
}

// ---------------- fallback path (atomic scatter) --------------------------
__global__ void k_scatter(const int* __restrict__ src, const int* __restrict__ dst,
                          const float* __restrict__ s, float* acc, int n_edges) {
    long long idx = (long long)blockIdx.x * blockDim.x + threadIdx.x;
    int e = (int)(idx >> 6);
    int f = (int)(idx & 63);
    if (e < n_edges) {
        int sv = src[e], dv = dst[e];
        atomicAdd(&acc[(size_t)dv * HIDDEN + f], s[(size_t)sv * HIDDEN + f]);
    }
}

#define G2_ROWS 16
__launch_bounds__(256)
__global__ void k_gemm2(const float* accIn, const float* __restrict__ W2,
                        const float* __restrict__ b1, const float* __restrict__ dinv,
                        float* __restrict__ s2, float* accOut, int n_nodes) {
    __shared__ float ldsW[HIDDEN * HIDDEN];
    const int tid = threadIdx.x;
    {
        const float4* Wg = (const float4*)W2;
        float4* Wl = (float4*)ldsW;
#pragma unroll
        for (int i = 0; i < 4; ++i) Wl[tid + i * 256] = Wg[tid + i * 256];
    }
    __syncthreads();
    const int lane = tid & 63;
    const int wave = tid >> 6;
    const float bias = b1[lane];
    for (int i = 0; i < 4; ++i) {
        int row = blockIdx.x * G2_ROWS + wave * 4 + i;
        if (row >= n_nodes) return;
        float d = dinv[row];
        float v = accIn[(size_t)row * HIDDEN + lane];
        float h = fmaxf(d * v + bias, 0.f);
        float a = 0.f;
#pragma unroll
        for (int k = 0; k < HIDDEN; ++k)
            a += __shfl(h, k, 64) * ldsW[k * HIDDEN + lane];
        float o = a * d;
        s2[(size_t)row * HIDDEN + lane] = o;
        accOut[(size_t)row * HIDDEN + lane] = o;
    }
}

__global__ void k_poolB(const float* __restrict__ acc, const float* __restrict__ b2,
                        const float* __restrict__ dinv, const float* __restrict__ Wfc,
                        const int* __restrict__ batch,
                        float* gsum, int* gcnt, int n_nodes) {
    __shared__ float lsum[256];
    __shared__ int   lcnt[256];
    int tid = threadIdx.x;
    if (tid < 256) { lsum[tid] = 0.f; lcnt[tid] = 0; }
    __syncthreads();
    int lane = tid & 63, wave = tid >> 6;
    for (int i = 0; i < 16; ++i) {
        int n = blockIdx.x * 64 + wave * 16 + i;
        if (n < n_nodes) {
            float d = dinv[n];
            float h = fmaxf(fmaf(d, acc[(size_t)n * HIDDEN + lane], b2[lane]), 0.f);
            float t = h * Wfc[lane];
#pragma unroll
            for (int off = 32; off; off >>= 1) t += __shfl_down(t, off, 64);
            if (lane == 0) {
                int g = batch[n];
                atomicAdd(&lsum[g], t);
                atomicAdd(&lcnt[g], 1);
            }
        }
    }
    __syncthreads();
    if (tid < 256 && lcnt[tid]) {
        atomicAdd(&gsum[tid], lsum[tid]);
        atomicAdd(&gcnt[tid], lcnt[tid]);
    }
}

__global__ void k_out(const float* __restrict__ gsum, const int* __restrict__ gcnt,
                      const float* __restrict__ bfc, float* out) {
    int g = threadIdx.x;
    if (g < 256) {
        float c = (float)(gcnt[g] > 1 ? gcnt[g] : 1);
        out[g] = gsum[g] / c + bfc[0];
    }
}

// ---------------------------------------------------------------------------
extern "C" void kernel_launch(void* const* d_in, const int* in_sizes, int n_in,
                              void* d_out, int out_size, void* d_ws, size_t ws_size,
                              hipStream_t stream) {
    const float* x   = (const float*)d_in[0];
    const int*   ei  = (const int*)d_in[1];
    const int*   bat = (const int*)d_in[2];
    const float* W1  = (const float*)d_in[3];
    const float* b1  = (const float*)d_in[4];
    const float* W2  = (const float*)d_in[5];
    const float* b2  = (const float*)d_in[6];
    const float* Wfc = (const float*)d_in[7];
    const float* bfc = (const float*)d_in[8];
    float* out = (float*)d_out;

    const int n_nodes = in_sizes[2];
    const int n_edges = in_sizes[1] / 2;
    const int* src = ei;
    const int* dst = ei + n_edges;

    char* w = (char*)d_ws;
    size_t off = 0;
    auto alloc = [&](size_t bytes) -> void* {
        void* p = w + off;
        off += (bytes + 255) & ~(size_t)255;
        return p;
    };
    int*   deg  = (int*)  alloc((size_t)n_nodes * sizeof(int));
    float* dinv = (float*)alloc((size_t)n_nodes * sizeof(float));
    float* bufA = (float*)alloc((size_t)n_nodes * HIDDEN * sizeof(float));
    float* bufB = (float*)alloc((size_t)n_nodes * HIDDEN * sizeof(float));
    float* gsum = (float*)alloc(256 * sizeof(float));
    int*   gcnt = (int*)  alloc(256 * sizeof(int));
    size_t base_need = off;
    // CSR extras
    const int nb_scan = (n_nodes + SCAN_ITEMS - 1) / SCAN_ITEMS;
    int* row_start = (int*)alloc(((size_t)n_nodes + 1) * sizeof(int));
    int* cursor    = (int*)alloc((size_t)n_nodes * sizeof(int));
    int* bsum      = (int*)alloc((size_t)nb_scan * sizeof(int));
    int* csr       = (int*)alloc(((size_t)n_edges + 64) * sizeof(int));
    size_t csr_need = off;
    (void)base_need; (void)n_in; (void)out_size;

    const bool use_csr = (ws_size >= csr_need);

    const int nb  = (n_nodes + 255) / 256;
    const int neb = (n_edges + 255) / 256;

    hipLaunchKernelGGL(k_init, dim3(nb), dim3(256), 0, stream, deg, gsum, gcnt, n_nodes);
    hipLaunchKernelGGL(k_deg, dim3(neb), dim3(256), 0, stream, dst, deg, n_edges);

    if (use_csr) {
        hipLaunchKernelGGL(k_scan1, dim3(nb_scan), dim3(256), 0, stream, deg, bsum, n_nodes);
        hipLaunchKernelGGL(k_scan2, dim3(1), dim3(64), 0, stream,
                           bsum, nb_scan, row_start, n_nodes, n_edges);
        hipLaunchKernelGGL(k_scan3, dim3(nb_scan), dim3(256), 0, stream,
                           deg, bsum, row_start, cursor, dinv, n_nodes);
        hipLaunchKernelGGL(k_fill, dim3(neb), dim3(256), 0, stream,
                           src, dst, cursor, csr, n_edges);
        hipLaunchKernelGGL(k_gemm1, dim3((n_nodes + G1_ROWS - 1) / G1_ROWS), dim3(256), 0, stream,
                           x, W1, dinv, bufA, (float*)nullptr, n_nodes);
        const int gb = (n_nodes + 4 * NPW - 1) / (4 * NPW);
        hipLaunchKernelGGL(k_layer1, dim3(gb), dim3(256), 0, stream,
                           bufA, row_start, csr, W2, b1, dinv, bufB, n_nodes);
        hipLaunchKernelGGL(k_layer2pool, dim3(gb), dim3(256), 0, stream,
                           bufB, row_start, csr, b2, dinv, Wfc, bat, gsum, gcnt, n_nodes);
    } else {
        hipLaunchKernelGGL(k_dinv, dim3(nb), dim3(256), 0, stream, deg, dinv, n_nodes);
        hipLaunchKernelGGL(k_gemm1, dim3((n_nodes + G1_ROWS - 1) / G1_ROWS), dim3(256), 0, stream,
                           x, W1, dinv, bufA, bufB, n_nodes);
        long long items = (long long)n_edges * 64;
        int sb = (int)((items + 255) / 256);
        hipLaunchKernelGGL(k_scatter, dim3(sb), dim3(256), 0, stream,
                           src, dst, bufA, bufB, n_edges);
        hipLaunchKernelGGL(k_gemm2, dim3((n_nodes + G2_ROWS - 1) / G2_ROWS), dim3(256), 0, stream,
                           bufB, W2, b1, dinv, bufA, bufB, n_nodes);
        hipLaunchKernelGGL(k_scatter, dim3(sb), dim3(256), 0, stream,
                           src, dst, bufA, bufB, n_edges);
        hipLaunchKernelGGL(k_poolB, dim3((n_nodes + 63) / 64), dim3(256), 0, stream,
                           bufB, b2, dinv, Wfc, bat, gsum, gcnt, n_nodes);
    }
    hipLaunchKernelGGL(k_out, dim3(1), dim3(256), 0, stream, gsum, gcnt, bfc, out);
}

// Round 3
// 699.639 us; speedup vs baseline: 2.3803x; 1.1362x over previous
//
#include <hip/hip_runtime.h>

#define HIDDEN 64
#define IN_DIM 512
#define SCAN_ITEMS 1024

typedef short v8s __attribute__((ext_vector_type(8)));
typedef float v4f __attribute__((ext_vector_type(4)));

static __device__ __forceinline__ unsigned short f2bf(float f) {
    unsigned int u = __float_as_uint(f);
    u = (u + 0x7FFF + ((u >> 16) & 1)) >> 16;   // RNE
    return (unsigned short)u;
}
static __device__ __forceinline__ float bf2f(unsigned short u) {
    return __uint_as_float(((unsigned int)u) << 16);
}

// ---------------- init: deg=1 (self loop), zero pool accumulators ----------
__global__ void k_init(int* deg, float* gsum, int* gcnt, int n_nodes) {
    int i = blockIdx.x * blockDim.x + threadIdx.x;
    if (i < n_nodes) deg[i] = 1;
    if (i < 256) { gsum[i] = 0.f; gcnt[i] = 0; }
}

// ---------------- in-degree histogram over dst -----------------------------
__global__ void k_deg(const int* __restrict__ dst, int* deg, int n_edges) {
    int e = blockIdx.x * blockDim.x + threadIdx.x;
    if (e < n_edges) atomicAdd(&deg[dst[e]], 1);
}

// ---------------- W1 -> Wt bf16 transpose [64][512] ------------------------
__global__ void k_prep(const float* __restrict__ W1, unsigned short* __restrict__ Wt) {
    int idx = blockIdx.x * 256 + threadIdx.x;      // 32768 total
    int n = idx >> 9, k = idx & 511;
    Wt[(size_t)n * 512 + k] = f2bf(W1[(size_t)k * 64 + n]);
}

// ---------------- CSR build: 3-kernel exclusive scan of (deg-1) ------------
__global__ void k_scan1(const int* __restrict__ deg, int* bsum, int n) {
    int b = blockIdx.x, t = threadIdx.x;
    int base = b * SCAN_ITEMS;
    int s = 0;
    for (int i = t; i < SCAN_ITEMS; i += 256) {
        int g = base + i;
        if (g < n) s += deg[g] - 1;
    }
#pragma unroll
    for (int off = 32; off; off >>= 1) s += __shfl_down(s, off, 64);
    __shared__ int ws[4];
    if ((t & 63) == 0) ws[t >> 6] = s;
    __syncthreads();
    if (t == 0) bsum[b] = ws[0] + ws[1] + ws[2] + ws[3];
}

__global__ void k_scan2(int* bsum, int nb, int* row_start, int n_nodes, int n_edges) {
    if (threadIdx.x == 0) {
        int run = 0;
        for (int i = 0; i < nb; ++i) { int v = bsum[i]; bsum[i] = run; run += v; }
        row_start[n_nodes] = n_edges;
    }
}

__launch_bounds__(256)
__global__ void k_scan3(const int* __restrict__ deg, const int* __restrict__ bsum_ex,
                        int* row_start, int* cursor, float* dinv, int n) {
    int b = blockIdx.x, t = threadIdx.x;
    int i0 = b * SCAN_ITEMS + t * 4;
    int c[4], sinc[4];
#pragma unroll
    for (int k = 0; k < 4; ++k) { int g = i0 + k; c[k] = (g < n) ? deg[g] - 1 : 0; }
    sinc[0] = c[0];
    sinc[1] = sinc[0] + c[1];
    sinc[2] = sinc[1] + c[2];
    sinc[3] = sinc[2] + c[3];
    int S = sinc[3];
    int v = S, lane = t & 63;
#pragma unroll
    for (int off = 1; off < 64; off <<= 1) {
        int u = __shfl_up(v, off, 64);
        if (lane >= off) v += u;
    }
    int wave_excl = v - S;
    __shared__ int wtot[4];
    if (lane == 63) wtot[t >> 6] = v;
    __syncthreads();
    int cross = 0;
    for (int w = 0; w < (t >> 6); ++w) cross += wtot[w];
    int base = bsum_ex[b] + cross + wave_excl;
#pragma unroll
    for (int k = 0; k < 4; ++k) {
        int g = i0 + k;
        if (g < n) {
            int rsv = base + sinc[k] - c[k];
            row_start[g] = rsv;
            cursor[g] = rsv;
            dinv[g] = rsqrtf((float)deg[g]);
        }
    }
}

__global__ void k_fill(const int* __restrict__ src, const int* __restrict__ dst,
                       int* cursor, int* csr, int n_edges) {
    int e = blockIdx.x * blockDim.x + threadIdx.x;
    if (e < n_edges) {
        int d = dst[e];
        int pos = atomicAdd(&cursor[d], 1);
        csr[pos] = src[e];
    }
}

// ---------------- GEMM1 (MFMA bf16): s1 = bf16(dinv .* (x @ W1)) -----------
// block = 256 thr (4 waves), 64 rows/block, K chunks of 128.
// LDS pitch 136 bf16 (272B) -> 2-way bank aliasing only (free).
__launch_bounds__(256)
__global__ void k_gemm1m(const float* __restrict__ x, const unsigned short* __restrict__ Wt,
                         const float* __restrict__ dinv, unsigned short* __restrict__ s1,
                         int n_nodes) {
    __shared__ __align__(16) unsigned short lX[64 * 136];   // 17408 B
    __shared__ __align__(16) unsigned short lW[64 * 136];   // 17408 B
    const int tid  = threadIdx.x;
    const int lane = tid & 63;
    const int w    = tid >> 6;
    const int quad = lane >> 4;
    const int m16  = lane & 15;
    const int row0 = blockIdx.x * 64;

    v4f acc[4];
#pragma unroll
    for (int b = 0; b < 4; ++b) acc[b] = (v4f){0.f, 0.f, 0.f, 0.f};

    for (int kc = 0; kc < IN_DIM; kc += 128) {
        __syncthreads();
        // stage X chunk: 64 rows x 128 cols, fp32 -> bf16
#pragma unroll
        for (int i = 0; i < 8; ++i) {
            int fidx = tid + i * 256;
            int r  = fidx >> 5;          // 0..63
            int c4 = fidx & 31;          // float4 index
            int gr = row0 + r;
            float4 v = make_float4(0.f, 0.f, 0.f, 0.f);
            if (gr < n_nodes) v = ((const float4*)(x + (size_t)gr * IN_DIM + kc))[c4];
            ushort4 u = make_ushort4(f2bf(v.x), f2bf(v.y), f2bf(v.z), f2bf(v.w));
            *(ushort4*)(lX + r * 136 + c4 * 4) = u;
        }
        // stage Wt chunk: 64 n x 128 k (already bf16)
#pragma unroll
        for (int i = 0; i < 4; ++i) {
            int idx = tid + i * 256;
            int n  = idx >> 4;
            int c8 = idx & 15;
            uint4 u = *(const uint4*)(Wt + (size_t)n * 512 + kc + c8 * 8);
            *(uint4*)(lW + n * 136 + c8 * 8) = u;
        }
        __syncthreads();
#pragma unroll
        for (int kk = 0; kk < 128; kk += 32) {
            v8s a = *(const v8s*)(lX + (w * 16 + m16) * 136 + kk + quad * 8);
#pragma unroll
            for (int b = 0; b < 4; ++b) {
                v8s bb = *(const v8s*)(lW + (b * 16 + m16) * 136 + kk + quad * 8);
                acc[b] = __builtin_amdgcn_mfma_f32_16x16x32_bf16(a, bb, acc[b], 0, 0, 0);
            }
        }
    }
    // epilogue: frags -> LDS (pitch 65: conflict-free) -> coalesced bf16 store
    __syncthreads();
    float* lC = (float*)lX;
#pragma unroll
    for (int b = 0; b < 4; ++b)
#pragma unroll
        for (int r = 0; r < 4; ++r) {
            int rowt = w * 16 + quad * 4 + r;
            lC[rowt * 65 + b * 16 + m16] = acc[b][r];
        }
    __syncthreads();
#pragma unroll
    for (int i = 0; i < 2; ++i) {
        int base = i * 2048 + tid * 8;
        int r = base >> 6;
        int c = base & 63;
        int gr = row0 + r;
        if (gr < n_nodes) {
            float d = dinv[gr];
            const float* p = lC + r * 65 + c;
            unsigned p0 = (unsigned)f2bf(p[0] * d) | ((unsigned)f2bf(p[1] * d) << 16);
            unsigned p1 = (unsigned)f2bf(p[2] * d) | ((unsigned)f2bf(p[3] * d) << 16);
            unsigned p2 = (unsigned)f2bf(p[4] * d) | ((unsigned)f2bf(p[5] * d) << 16);
            unsigned p3 = (unsigned)f2bf(p[6] * d) | ((unsigned)f2bf(p[7] * d) << 16);
            *(uint4*)(s1 + (size_t)gr * 64 + c) = make_uint4(p0, p1, p2, p3);
        }
    }
}

// ---------------- layer1: CSR gather (bf16) + finalize + GEMM2 -------------
#define NPW 8   // nodes per wave

__launch_bounds__(256)
__global__ void k_layer1(const unsigned short* __restrict__ sin, const int* __restrict__ row_start,
                         const int* __restrict__ csr, const float* __restrict__ W2,
                         const float* __restrict__ b1, const float* __restrict__ dinv,
                         unsigned short* __restrict__ sout, int n_nodes) {
    __shared__ float ldsW[HIDDEN * HIDDEN];
    const int tid = threadIdx.x;
    {
        const float4* Wg = (const float4*)W2;
        float4* Wl = (float4*)ldsW;
#pragma unroll
        for (int i = 0; i < 4; ++i) Wl[tid + i * 256] = Wg[tid + i * 256];
    }
    __syncthreads();
    const int lane = tid & 63;
    const int wave = tid >> 6;
    const float bias = b1[lane];
    const int n0 = (blockIdx.x * 4 + wave) * NPW;
    for (int i = 0; i < NPW; ++i) {
        int n = n0 + i;
        if (n >= n_nodes) break;
        int rs = row_start[n], re = row_start[n + 1];
        float acc = bf2f(sin[(size_t)n * HIDDEN + lane]);   // self loop
        for (int base = rs; base < re; base += 64) {
            int idx = csr[base + lane];                     // padded allocation
            int m = re - base; if (m > 64) m = 64;
            int j = 0;
            for (; j + 4 <= m; j += 4) {
                int a0 = __shfl(idx, j, 64),     a1 = __shfl(idx, j + 1, 64);
                int a2 = __shfl(idx, j + 2, 64), a3 = __shfl(idx, j + 3, 64);
                float v0 = bf2f(sin[(size_t)a0 * HIDDEN + lane]);
                float v1 = bf2f(sin[(size_t)a1 * HIDDEN + lane]);
                float v2 = bf2f(sin[(size_t)a2 * HIDDEN + lane]);
                float v3 = bf2f(sin[(size_t)a3 * HIDDEN + lane]);
                acc += (v0 + v1) + (v2 + v3);
            }
            for (; j < m; ++j) {
                int a0 = __shfl(idx, j, 64);
                acc += bf2f(sin[(size_t)a0 * HIDDEN + lane]);
            }
        }
        float d = dinv[n];
        float h = fmaxf(fmaf(d, acc, bias), 0.f);
        float a = 0.f;
#pragma unroll
        for (int k = 0; k < HIDDEN; ++k)
            a = fmaf(__shfl(h, k, 64), ldsW[k * HIDDEN + lane], a);
        sout[(size_t)n * HIDDEN + lane] = f2bf(a * d);
    }
}

// ---------------- layer2: CSR gather (bf16) + finalize + Wfc dot + pool ----
__launch_bounds__(256)
__global__ void k_layer2pool(const unsigned short* __restrict__ sin, const int* __restrict__ row_start,
                             const int* __restrict__ csr, const float* __restrict__ b2,
                             const float* __restrict__ dinv, const float* __restrict__ Wfc,
                             const int* __restrict__ batch,
                             float* gsum, int* gcnt, int n_nodes) {
    __shared__ float lsum[256];
    __shared__ int   lcnt[256];
    const int tid = threadIdx.x;
    if (tid < 256) { lsum[tid] = 0.f; lcnt[tid] = 0; }
    __syncthreads();
    const int lane = tid & 63;
    const int wave = tid >> 6;
    const float bias = b2[lane];
    const float wf = Wfc[lane];
    const int n0 = (blockIdx.x * 4 + wave) * NPW;
    for (int i = 0; i < NPW; ++i) {
        int n = n0 + i;
        if (n >= n_nodes) break;
        int rs = row_start[n], re = row_start[n + 1];
        float acc = bf2f(sin[(size_t)n * HIDDEN + lane]);
        for (int base = rs; base < re; base += 64) {
            int idx = csr[base + lane];
            int m = re - base; if (m > 64) m = 64;
            int j = 0;
            for (; j + 4 <= m; j += 4) {
                int a0 = __shfl(idx, j, 64),     a1 = __shfl(idx, j + 1, 64);
                int a2 = __shfl(idx, j + 2, 64), a3 = __shfl(idx, j + 3, 64);
                float v0 = bf2f(sin[(size_t)a0 * HIDDEN + lane]);
                float v1 = bf2f(sin[(size_t)a1 * HIDDEN + lane]);
                float v2 = bf2f(sin[(size_t)a2 * HIDDEN + lane]);
                float v3 = bf2f(sin[(size_t)a3 * HIDDEN + lane]);
                acc += (v0 + v1) + (v2 + v3);
            }
            for (; j < m; ++j) {
                int a0 = __shfl(idx, j, 64);
                acc += bf2f(sin[(size_t)a0 * HIDDEN + lane]);
            }
        }
        float d = dinv[n];
        float h = fmaxf(fmaf(d, acc, bias), 0.f);
        float t = h * wf;
#pragma unroll
        for (int off = 32; off; off >>= 1) t += __shfl_down(t, off, 64);
        if (lane == 0) {
            int g = batch[n];
            atomicAdd(&lsum[g], t);
            atomicAdd(&lcnt[g], 1);
        }
    }
    __syncthreads();
    if (tid < 256 && lcnt[tid]) {
        atomicAdd(&gsum[tid], lsum[tid]);
        atomicAdd(&gcnt[tid], lcnt[tid]);
    }
}

__global__ void k_out(const float* __restrict__ gsum, const int* __restrict__ gcnt,
                      const float* __restrict__ bfc, float* out) {
    int g = threadIdx.x;
    if (g < 256) {
        float c = (float)(gcnt[g] > 1 ? gcnt[g] : 1);
        out[g] = gsum[g] / c + bfc[0];
    }
}

// ---------------------------------------------------------------------------
extern "C" void kernel_launch(void* const* d_in, const int* in_sizes, int n_in,
                              void* d_out, int out_size, void* d_ws, size_t ws_size,
                              hipStream_t stream) {
    const float* x   = (const float*)d_in[0];
    const int*   ei  = (const int*)d_in[1];
    const int*   bat = (const int*)d_in[2];
    const float* W1  = (const float*)d_in[3];
    const float* b1  = (const float*)d_in[4];
    const float* W2  = (const float*)d_in[5];
    const float* b2  = (const float*)d_in[6];
    const float* Wfc = (const float*)d_in[7];
    const float* bfc = (const float*)d_in[8];
    float* out = (float*)d_out;

    const int n_nodes = in_sizes[2];
    const int n_edges = in_sizes[1] / 2;
    const int* src = ei;
    const int* dst = ei + n_edges;

    char* w = (char*)d_ws;
    size_t off = 0;
    auto alloc = [&](size_t bytes) -> void* {
        void* p = w + off;
        off += (bytes + 255) & ~(size_t)255;
        return p;
    };
    int*   deg  = (int*)  alloc((size_t)n_nodes * sizeof(int));
    float* dinv = (float*)alloc((size_t)n_nodes * sizeof(float));
    unsigned short* bufA = (unsigned short*)alloc((size_t)n_nodes * HIDDEN * 2);  // s1
    unsigned short* bufB = (unsigned short*)alloc((size_t)n_nodes * HIDDEN * 2);  // s2
    unsigned short* Wt   = (unsigned short*)alloc((size_t)HIDDEN * IN_DIM * 2);
    float* gsum = (float*)alloc(256 * sizeof(float));
    int*   gcnt = (int*)  alloc(256 * sizeof(int));
    const int nb_scan = (n_nodes + SCAN_ITEMS - 1) / SCAN_ITEMS;
    int* row_start = (int*)alloc(((size_t)n_nodes + 1) * sizeof(int));
    int* cursor    = (int*)alloc((size_t)n_nodes * sizeof(int));
    int* bsum      = (int*)alloc((size_t)nb_scan * sizeof(int));
    int* csr       = (int*)alloc(((size_t)n_edges + 64) * sizeof(int));
    (void)ws_size; (void)n_in; (void)out_size;

    const int nb  = (n_nodes + 255) / 256;
    const int neb = (n_edges + 255) / 256;

    hipLaunchKernelGGL(k_init, dim3(nb), dim3(256), 0, stream, deg, gsum, gcnt, n_nodes);
    hipLaunchKernelGGL(k_deg, dim3(neb), dim3(256), 0, stream, dst, deg, n_edges);
    hipLaunchKernelGGL(k_prep, dim3((HIDDEN * IN_DIM) / 256), dim3(256), 0, stream, W1, Wt);
    hipLaunchKernelGGL(k_scan1, dim3(nb_scan), dim3(256), 0, stream, deg, bsum, n_nodes);
    hipLaunchKernelGGL(k_scan2, dim3(1), dim3(64), 0, stream,
                       bsum, nb_scan, row_start, n_nodes, n_edges);
    hipLaunchKernelGGL(k_scan3, dim3(nb_scan), dim3(256), 0, stream,
                       deg, bsum, row_start, cursor, dinv, n_nodes);
    hipLaunchKernelGGL(k_fill, dim3(neb), dim3(256), 0, stream,
                       src, dst, cursor, csr, n_edges);
    hipLaunchKernelGGL(k_gemm1m, dim3((n_nodes + 63) / 64), dim3(256), 0, stream,
                       x, Wt, dinv, bufA, n_nodes);
    const int gb = (n_nodes + 4 * NPW - 1) / (4 * NPW);
    hipLaunchKernelGGL(k_layer1, dim3(gb), dim3(256), 0, stream,
                       bufA, row_start, csr, W2, b1, dinv, bufB, n_nodes);
    hipLaunchKernelGGL(k_layer2pool, dim3(gb), dim3(256), 0, stream,
                       bufB, row_start, csr, b2, dinv, Wfc, bat, gsum, gcnt, n_nodes);
    hipLaunchKernelGGL(k_out, dim3(1), dim3(256), 0, stream, gsum, gcnt, bfc, out);
}

// Round 4
// 646.040 us; speedup vs baseline: 2.5778x; 1.0830x over previous
//
#include <hip/hip_runtime.h>

#define HIDDEN 64
#define IN_DIM 512
#define SCAN_ITEMS 1024

typedef short v8s __attribute__((ext_vector_type(8)));
typedef float v4f __attribute__((ext_vector_type(4)));

static __device__ __forceinline__ unsigned short f2bf(float f) {
    unsigned int u = __float_as_uint(f);
    u = (u + 0x7FFF + ((u >> 16) & 1)) >> 16;   // RNE
    return (unsigned short)u;
}
static __device__ __forceinline__ float bf2f(unsigned short u) {
    return __uint_as_float(((unsigned int)u) << 16);
}
static __device__ __forceinline__ float bflo(unsigned u) { return __uint_as_float(u << 16); }
static __device__ __forceinline__ float bfhi(unsigned u) { return __uint_as_float(u & 0xffff0000u); }

// ---------------- init: deg=1 (self loop), zero pool accumulators ----------
__global__ void k_init(int* deg, float* gsum, int* gcnt, int n_nodes) {
    int i = blockIdx.x * blockDim.x + threadIdx.x;
    if (i < n_nodes) deg[i] = 1;
    if (i < 256) { gsum[i] = 0.f; gcnt[i] = 0; }
}

// ---------------- in-degree histogram over dst -----------------------------
__global__ void k_deg(const int* __restrict__ dst, int* deg, int n_edges) {
    int e = blockIdx.x * blockDim.x + threadIdx.x;
    if (e < n_edges) atomicAdd(&deg[dst[e]], 1);
}

// ---------------- W1 -> Wt bf16 transpose [64][512] ------------------------
__global__ void k_prep(const float* __restrict__ W1, unsigned short* __restrict__ Wt) {
    int idx = blockIdx.x * 256 + threadIdx.x;      // 32768 total
    int n = idx >> 9, k = idx & 511;
    Wt[(size_t)n * 512 + k] = f2bf(W1[(size_t)k * 64 + n]);
}

// ---------------- CSR build: 3-kernel exclusive scan of (deg-1) ------------
__global__ void k_scan1(const int* __restrict__ deg, int* bsum, int n) {
    int b = blockIdx.x, t = threadIdx.x;
    int base = b * SCAN_ITEMS;
    int s = 0;
    for (int i = t; i < SCAN_ITEMS; i += 256) {
        int g = base + i;
        if (g < n) s += deg[g] - 1;
    }
#pragma unroll
    for (int off = 32; off; off >>= 1) s += __shfl_down(s, off, 64);
    __shared__ int ws[4];
    if ((t & 63) == 0) ws[t >> 6] = s;
    __syncthreads();
    if (t == 0) bsum[b] = ws[0] + ws[1] + ws[2] + ws[3];
}

__global__ void k_scan2(int* bsum, int nb, int* row_start, int n_nodes, int n_edges) {
    if (threadIdx.x == 0) {
        int run = 0;
        for (int i = 0; i < nb; ++i) { int v = bsum[i]; bsum[i] = run; run += v; }
        row_start[n_nodes] = n_edges;
    }
}

__launch_bounds__(256)
__global__ void k_scan3(const int* __restrict__ deg, const int* __restrict__ bsum_ex,
                        int* row_start, int* cursor, float* dinv, int n) {
    int b = blockIdx.x, t = threadIdx.x;
    int i0 = b * SCAN_ITEMS + t * 4;
    int c[4], sinc[4];
#pragma unroll
    for (int k = 0; k < 4; ++k) { int g = i0 + k; c[k] = (g < n) ? deg[g] - 1 : 0; }
    sinc[0] = c[0];
    sinc[1] = sinc[0] + c[1];
    sinc[2] = sinc[1] + c[2];
    sinc[3] = sinc[2] + c[3];
    int S = sinc[3];
    int v = S, lane = t & 63;
#pragma unroll
    for (int off = 1; off < 64; off <<= 1) {
        int u = __shfl_up(v, off, 64);
        if (lane >= off) v += u;
    }
    int wave_excl = v - S;
    __shared__ int wtot[4];
    if (lane == 63) wtot[t >> 6] = v;
    __syncthreads();
    int cross = 0;
    for (int w = 0; w < (t >> 6); ++w) cross += wtot[w];
    int base = bsum_ex[b] + cross + wave_excl;
#pragma unroll
    for (int k = 0; k < 4; ++k) {
        int g = i0 + k;
        if (g < n) {
            int rsv = base + sinc[k] - c[k];
            row_start[g] = rsv;
            cursor[g] = rsv;
            dinv[g] = rsqrtf((float)deg[g]);
        }
    }
}

__global__ void k_fill(const int* __restrict__ src, const int* __restrict__ dst,
                       int* cursor, int* csr, int n_edges) {
    int e = blockIdx.x * blockDim.x + threadIdx.x;
    if (e < n_edges) {
        int d = dst[e];
        int pos = atomicAdd(&cursor[d], 1);
        csr[pos] = src[e];
    }
}

// ---------------- GEMM1 (MFMA bf16): s1 = bf16(dinv .* (x @ W1)) -----------
__launch_bounds__(256)
__global__ void k_gemm1m(const float* __restrict__ x, const unsigned short* __restrict__ Wt,
                         const float* __restrict__ dinv, unsigned short* __restrict__ s1,
                         int n_nodes) {
    __shared__ __align__(16) unsigned short lX[64 * 136];   // 17408 B
    __shared__ __align__(16) unsigned short lW[64 * 136];   // 17408 B
    const int tid  = threadIdx.x;
    const int lane = tid & 63;
    const int w    = tid >> 6;
    const int quad = lane >> 4;
    const int m16  = lane & 15;
    const int row0 = blockIdx.x * 64;

    v4f acc[4];
#pragma unroll
    for (int b = 0; b < 4; ++b) acc[b] = (v4f){0.f, 0.f, 0.f, 0.f};

    for (int kc = 0; kc < IN_DIM; kc += 128) {
        __syncthreads();
#pragma unroll
        for (int i = 0; i < 8; ++i) {
            int fidx = tid + i * 256;
            int r  = fidx >> 5;
            int c4 = fidx & 31;
            int gr = row0 + r;
            float4 v = make_float4(0.f, 0.f, 0.f, 0.f);
            if (gr < n_nodes) v = ((const float4*)(x + (size_t)gr * IN_DIM + kc))[c4];
            ushort4 u = make_ushort4(f2bf(v.x), f2bf(v.y), f2bf(v.z), f2bf(v.w));
            *(ushort4*)(lX + r * 136 + c4 * 4) = u;
        }
#pragma unroll
        for (int i = 0; i < 4; ++i) {
            int idx = tid + i * 256;
            int n  = idx >> 4;
            int c8 = idx & 15;
            uint4 u = *(const uint4*)(Wt + (size_t)n * 512 + kc + c8 * 8);
            *(uint4*)(lW + n * 136 + c8 * 8) = u;
        }
        __syncthreads();
#pragma unroll
        for (int kk = 0; kk < 128; kk += 32) {
            v8s a = *(const v8s*)(lX + (w * 16 + m16) * 136 + kk + quad * 8);
#pragma unroll
            for (int b = 0; b < 4; ++b) {
                v8s bb = *(const v8s*)(lW + (b * 16 + m16) * 136 + kk + quad * 8);
                acc[b] = __builtin_amdgcn_mfma_f32_16x16x32_bf16(a, bb, acc[b], 0, 0, 0);
            }
        }
    }
    __syncthreads();
    float* lC = (float*)lX;
#pragma unroll
    for (int b = 0; b < 4; ++b)
#pragma unroll
        for (int r = 0; r < 4; ++r) {
            int rowt = w * 16 + quad * 4 + r;
            lC[rowt * 65 + b * 16 + m16] = acc[b][r];
        }
    __syncthreads();
#pragma unroll
    for (int i = 0; i < 2; ++i) {
        int base = i * 2048 + tid * 8;
        int r = base >> 6;
        int c = base & 63;
        int gr = row0 + r;
        if (gr < n_nodes) {
            float d = dinv[gr];
            const float* p = lC + r * 65 + c;
            unsigned p0 = (unsigned)f2bf(p[0] * d) | ((unsigned)f2bf(p[1] * d) << 16);
            unsigned p1 = (unsigned)f2bf(p[2] * d) | ((unsigned)f2bf(p[3] * d) << 16);
            unsigned p2 = (unsigned)f2bf(p[4] * d) | ((unsigned)f2bf(p[5] * d) << 16);
            unsigned p3 = (unsigned)f2bf(p[6] * d) | ((unsigned)f2bf(p[7] * d) << 16);
            *(uint4*)(s1 + (size_t)gr * 64 + c) = make_uint4(p0, p1, p2, p3);
        }
    }
}

// ---------------- layer1: packed CSR gather + finalize + GEMM2 -------------
// wave = 4 groups x 16 lanes; lane holds features 4l..4l+3.
#define NPW 4   // nodes per wave

__launch_bounds__(256)
__global__ void k_layer1(const unsigned short* __restrict__ sin, const int* __restrict__ row_start,
                         const int* __restrict__ csr, const float* __restrict__ W2,
                         const float* __restrict__ b1, const float* __restrict__ dinv,
                         unsigned short* __restrict__ sout, int n_nodes) {
    __shared__ float ldsW[HIDDEN * HIDDEN];   // [k][f] 16 KB
    const int tid = threadIdx.x;
    {
        const float4* Wg = (const float4*)W2;
        float4* Wl = (float4*)ldsW;
#pragma unroll
        for (int i = 0; i < 4; ++i) Wl[tid + i * 256] = Wg[tid + i * 256];
    }
    __syncthreads();
    const int lane = tid & 63;
    const int wave = tid >> 6;
    const int g = lane >> 4;
    const int l = lane & 15;
    const float4 b4 = ((const float4*)b1)[l];
    const int n0 = (blockIdx.x * 4 + wave) * NPW;
    for (int i = 0; i < NPW; ++i) {
        int n = n0 + i;
        if (n >= n_nodes) break;
        int rs = row_start[n], re = row_start[n + 1];
        float4 acc = make_float4(0.f, 0.f, 0.f, 0.f);   // group-partial
        for (int base = rs; base < re; base += 64) {
            int idx = csr[base + lane];
            int m = re - base; if (m > 64) m = 64;
            for (int j = 0; j < m; j += 4) {
                int myj = j + g;
                int a = __shfl(idx, myj, 64);
                if (myj < m) {
                    uint2 u = *(const uint2*)(sin + (size_t)a * HIDDEN + l * 4);
                    acc.x += bflo(u.x); acc.y += bfhi(u.x);
                    acc.z += bflo(u.y); acc.w += bfhi(u.y);
                }
            }
        }
        // fold groups
        acc.x += __shfl_xor(acc.x, 16, 64); acc.y += __shfl_xor(acc.y, 16, 64);
        acc.z += __shfl_xor(acc.z, 16, 64); acc.w += __shfl_xor(acc.w, 16, 64);
        acc.x += __shfl_xor(acc.x, 32, 64); acc.y += __shfl_xor(acc.y, 32, 64);
        acc.z += __shfl_xor(acc.z, 32, 64); acc.w += __shfl_xor(acc.w, 32, 64);
        // self loop
        {
            uint2 u = *(const uint2*)(sin + (size_t)n * HIDDEN + l * 4);
            acc.x += bflo(u.x); acc.y += bfhi(u.x);
            acc.z += bflo(u.y); acc.w += bfhi(u.y);
        }
        float d = dinv[n];
        float4 h;
        h.x = fmaxf(fmaf(d, acc.x, b4.x), 0.f);
        h.y = fmaxf(fmaf(d, acc.y, b4.y), 0.f);
        h.z = fmaxf(fmaf(d, acc.z, b4.z), 0.f);
        h.w = fmaxf(fmaf(d, acc.w, b4.w), 0.f);
        // GEMM2, k-partitioned: group g handles k = 16g..16g+15
        float4 a4 = make_float4(0.f, 0.f, 0.f, 0.f);
#pragma unroll
        for (int kk = 0; kk < 16; ++kk) {
            int srcl = 4 * g + (kk >> 2);   // lane (group 0) holding h[16g+kk]
            float hk;
            if ((kk & 3) == 0)      hk = __shfl(h.x, srcl, 64);
            else if ((kk & 3) == 1) hk = __shfl(h.y, srcl, 64);
            else if ((kk & 3) == 2) hk = __shfl(h.z, srcl, 64);
            else                    hk = __shfl(h.w, srcl, 64);
            float4 w4 = *(const float4*)(ldsW + (16 * g + kk) * HIDDEN + 4 * l);
            a4.x = fmaf(hk, w4.x, a4.x);
            a4.y = fmaf(hk, w4.y, a4.y);
            a4.z = fmaf(hk, w4.z, a4.z);
            a4.w = fmaf(hk, w4.w, a4.w);
        }
        a4.x += __shfl_xor(a4.x, 16, 64); a4.y += __shfl_xor(a4.y, 16, 64);
        a4.z += __shfl_xor(a4.z, 16, 64); a4.w += __shfl_xor(a4.w, 16, 64);
        a4.x += __shfl_xor(a4.x, 32, 64); a4.y += __shfl_xor(a4.y, 32, 64);
        a4.z += __shfl_xor(a4.z, 32, 64); a4.w += __shfl_xor(a4.w, 32, 64);
        if (g == 0) {
            unsigned p0 = (unsigned)f2bf(a4.x * d) | ((unsigned)f2bf(a4.y * d) << 16);
            unsigned p1 = (unsigned)f2bf(a4.z * d) | ((unsigned)f2bf(a4.w * d) << 16);
            *(uint2*)(sout + (size_t)n * HIDDEN + l * 4) = make_uint2(p0, p1);
        }
    }
}

// ---------------- layer2: packed CSR gather + finalize + Wfc dot + pool ----
__launch_bounds__(256)
__global__ void k_layer2pool(const unsigned short* __restrict__ sin, const int* __restrict__ row_start,
                             const int* __restrict__ csr, const float* __restrict__ b2,
                             const float* __restrict__ dinv, const float* __restrict__ Wfc,
                             const int* __restrict__ batch,
                             float* gsum, int* gcnt, int n_nodes) {
    __shared__ float lsum[256];
    __shared__ int   lcnt[256];
    const int tid = threadIdx.x;
    lsum[tid] = 0.f; lcnt[tid] = 0;
    __syncthreads();
    const int lane = tid & 63;
    const int wave = tid >> 6;
    const int g = lane >> 4;
    const int l = lane & 15;
    const float4 b4  = ((const float4*)b2)[l];
    const float4 wf4 = ((const float4*)Wfc)[l];
    const int n0 = (blockIdx.x * 4 + wave) * NPW;
    for (int i = 0; i < NPW; ++i) {
        int n = n0 + i;
        if (n >= n_nodes) break;
        int rs = row_start[n], re = row_start[n + 1];
        float4 acc = make_float4(0.f, 0.f, 0.f, 0.f);
        for (int base = rs; base < re; base += 64) {
            int idx = csr[base + lane];
            int m = re - base; if (m > 64) m = 64;
            for (int j = 0; j < m; j += 4) {
                int myj = j + g;
                int a = __shfl(idx, myj, 64);
                if (myj < m) {
                    uint2 u = *(const uint2*)(sin + (size_t)a * HIDDEN + l * 4);
                    acc.x += bflo(u.x); acc.y += bfhi(u.x);
                    acc.z += bflo(u.y); acc.w += bfhi(u.y);
                }
            }
        }
        acc.x += __shfl_xor(acc.x, 16, 64); acc.y += __shfl_xor(acc.y, 16, 64);
        acc.z += __shfl_xor(acc.z, 16, 64); acc.w += __shfl_xor(acc.w, 16, 64);
        acc.x += __shfl_xor(acc.x, 32, 64); acc.y += __shfl_xor(acc.y, 32, 64);
        acc.z += __shfl_xor(acc.z, 32, 64); acc.w += __shfl_xor(acc.w, 32, 64);
        {
            uint2 u = *(const uint2*)(sin + (size_t)n * HIDDEN + l * 4);
            acc.x += bflo(u.x); acc.y += bfhi(u.x);
            acc.z += bflo(u.y); acc.w += bfhi(u.y);
        }
        float d = dinv[n];
        float t = fmaxf(fmaf(d, acc.x, b4.x), 0.f) * wf4.x
                + fmaxf(fmaf(d, acc.y, b4.y), 0.f) * wf4.y
                + fmaxf(fmaf(d, acc.z, b4.z), 0.f) * wf4.z
                + fmaxf(fmaf(d, acc.w, b4.w), 0.f) * wf4.w;
#pragma unroll
        for (int off = 32; off; off >>= 1) t += __shfl_down(t, off, 64);
        if (lane == 0) {
            int gr = batch[n];
            atomicAdd(&lsum[gr], t * 0.25f);   // groups replicate features 4x
            atomicAdd(&lcnt[gr], 1);
        }
    }
    __syncthreads();
    if (lcnt[tid]) {
        atomicAdd(&gsum[tid], lsum[tid]);
        atomicAdd(&gcnt[tid], lcnt[tid]);
    }
}

__global__ void k_out(const float* __restrict__ gsum, const int* __restrict__ gcnt,
                      const float* __restrict__ bfc, float* out) {
    int g = threadIdx.x;
    if (g < 256) {
        float c = (float)(gcnt[g] > 1 ? gcnt[g] : 1);
        out[g] = gsum[g] / c + bfc[0];
    }
}

// ---------------------------------------------------------------------------
extern "C" void kernel_launch(void* const* d_in, const int* in_sizes, int n_in,
                              void* d_out, int out_size, void* d_ws, size_t ws_size,
                              hipStream_t stream) {
    const float* x   = (const float*)d_in[0];
    const int*   ei  = (const int*)d_in[1];
    const int*   bat = (const int*)d_in[2];
    const float* W1  = (const float*)d_in[3];
    const float* b1  = (const float*)d_in[4];
    const float* W2  = (const float*)d_in[5];
    const float* b2  = (const float*)d_in[6];
    const float* Wfc = (const float*)d_in[7];
    const float* bfc = (const float*)d_in[8];
    float* out = (float*)d_out;

    const int n_nodes = in_sizes[2];
    const int n_edges = in_sizes[1] / 2;
    const int* src = ei;
    const int* dst = ei + n_edges;

    char* w = (char*)d_ws;
    size_t off = 0;
    auto alloc = [&](size_t bytes) -> void* {
        void* p = w + off;
        off += (bytes + 255) & ~(size_t)255;
        return p;
    };
    int*   deg  = (int*)  alloc((size_t)n_nodes * sizeof(int));
    float* dinv = (float*)alloc((size_t)n_nodes * sizeof(float));
    unsigned short* bufA = (unsigned short*)alloc((size_t)n_nodes * HIDDEN * 2);
    unsigned short* bufB = (unsigned short*)alloc((size_t)n_nodes * HIDDEN * 2);
    unsigned short* Wt   = (unsigned short*)alloc((size_t)HIDDEN * IN_DIM * 2);
    float* gsum = (float*)alloc(256 * sizeof(float));
    int*   gcnt = (int*)  alloc(256 * sizeof(int));
    const int nb_scan = (n_nodes + SCAN_ITEMS - 1) / SCAN_ITEMS;
    int* row_start = (int*)alloc(((size_t)n_nodes + 1) * sizeof(int));
    int* cursor    = (int*)alloc((size_t)n_nodes * sizeof(int));
    int* bsum      = (int*)alloc((size_t)nb_scan * sizeof(int));
    int* csr       = (int*)alloc(((size_t)n_edges + 64) * sizeof(int));
    (void)ws_size; (void)n_in; (void)out_size;

    const int nb  = (n_nodes + 255) / 256;
    const int neb = (n_edges + 255) / 256;

    hipLaunchKernelGGL(k_init, dim3(nb), dim3(256), 0, stream, deg, gsum, gcnt, n_nodes);
    hipLaunchKernelGGL(k_deg, dim3(neb), dim3(256), 0, stream, dst, deg, n_edges);
    hipLaunchKernelGGL(k_prep, dim3((HIDDEN * IN_DIM) / 256), dim3(256), 0, stream, W1, Wt);
    hipLaunchKernelGGL(k_scan1, dim3(nb_scan), dim3(256), 0, stream, deg, bsum, n_nodes);
    hipLaunchKernelGGL(k_scan2, dim3(1), dim3(64), 0, stream,
                       bsum, nb_scan, row_start, n_nodes, n_edges);
    hipLaunchKernelGGL(k_scan3, dim3(nb_scan), dim3(256), 0, stream,
                       deg, bsum, row_start, cursor, dinv, n_nodes);
    hipLaunchKernelGGL(k_fill, dim3(neb), dim3(256), 0, stream,
                       src, dst, cursor, csr, n_edges);
    hipLaunchKernelGGL(k_gemm1m, dim3((n_nodes + 63) / 64), dim3(256), 0, stream,
                       x, Wt, dinv, bufA, n_nodes);
    const int gb = (n_nodes + 4 * NPW - 1) / (4 * NPW);
    hipLaunchKernelGGL(k_layer1, dim3(gb), dim3(256), 0, stream,
                       bufA, row_start, csr, W2, b1, dinv, bufB, n_nodes);
    hipLaunchKernelGGL(k_layer2pool, dim3(gb), dim3(256), 0, stream,
                       bufB, row_start, csr, b2, dinv, Wfc, bat, gsum, gcnt, n_nodes);
    hipLaunchKernelGGL(k_out, dim3(1), dim3(256), 0, stream, gsum, gcnt, bfc, out);
}